// Round 5
// baseline (4661.327 us; speedup 1.0000x reference)
//
#include <hip/hip_runtime.h>

typedef unsigned short ushort_t;
typedef __attribute__((ext_vector_type(8))) short short8;   // 8 bf16 in 4 VGPRs
typedef __attribute__((ext_vector_type(4))) float f32x4;

#define B_ 32
#define T_ 512
#define H_ 512
#define CH_ 16     // output channels per GRU workgroup (32 WGs * 16 = 512)

// ---------- bf16 helpers ----------
__device__ __forceinline__ float bf2f(ushort_t u) {
  union { unsigned int i; float f; } v; v.i = ((unsigned int)u) << 16; return v.f;
}
__device__ __forceinline__ ushort_t f2bf(float f) {
  union { float fv; unsigned int i; } v; v.fv = f;
  unsigned int x = v.i;
  x += 0x7fffu + ((x >> 16) & 1u);   // round-to-nearest-even
  return (ushort_t)(x >> 16);
}

// fast gate activations: v_exp + v_rcp (approx, ~1ulp; bf16 output tolerant)
__device__ __forceinline__ float fsig(float a) {
  return __builtin_amdgcn_rcpf(1.f + __expf(-a));
}
__device__ __forceinline__ float ftanh(float a) {
  return 1.f - 2.f * __builtin_amdgcn_rcpf(1.f + __expf(2.f * a));  // sat: +/-1
}

// ---------- coherent (LLC) 16B load/store via sc0 sc1 ----------
__device__ __forceinline__ void cload16(short8& dst, const ushort_t* p) {
  asm volatile("global_load_dwordx4 %0, %1, off sc0 sc1"
               : "=v"(dst) : "v"(p) : "memory");
}
__device__ __forceinline__ void cstore16(const short8& v, ushort_t* p) {
  asm volatile("global_store_dwordx4 %1, %0, off sc0 sc1"
               :: "v"(v), "v"(p) : "memory");
}
#define WAIT_VM0 asm volatile("s_waitcnt vmcnt(0)" ::: "memory")
__device__ __forceinline__ void vfence(short8& v) { asm volatile("" : "+v"(v)); }

// ---------- flag rows: nf per-wave flags per step; poller = coalesced load + ballot
__device__ __forceinline__ void poll_row(const int* row, int nf) {
  const int lane = threadIdx.x & 63;
  if (nf > 64) {
    for (;;) {
      int a = __hip_atomic_load(row + lane,      __ATOMIC_RELAXED, __HIP_MEMORY_SCOPE_AGENT);
      int b = __hip_atomic_load(row + 64 + lane, __ATOMIC_RELAXED, __HIP_MEMORY_SCOPE_AGENT);
      if (__all(a != 0 && b != 0)) break;
      __builtin_amdgcn_s_sleep(1);
    }
  } else {
    for (;;) {
      int a = (lane < nf)
            ? __hip_atomic_load(row + lane, __ATOMIC_RELAXED, __HIP_MEMORY_SCOPE_AGENT) : 1;
      if (__all(a != 0)) break;
      __builtin_amdgcn_s_sleep(1);
    }
  }
  asm volatile("" ::: "memory");   // no hoisting data loads above the poll
}

// ---------- prep kernels ----------
__global__ void prep_w(const float* __restrict__ Wih, const float* __restrict__ Whh,
                       ushort_t* __restrict__ WihBf, ushort_t* __restrict__ WhhBf) {
  int i = blockIdx.x * 256 + threadIdx.x;
  WihBf[i] = f2bf(Wih[i]);
  WhhBf[i] = f2bf(Whh[i]);
}
__global__ void prep_x(const float* __restrict__ x, ushort_t* __restrict__ xA) {
  int i = blockIdx.x * 256 + threadIdx.x;
  int h  = i & (H_ - 1);
  int tb = i >> 9;
  int b  = tb & (B_ - 1);
  int t  = tb >> 5;
  xA[i] = f2bf(x[((size_t)b * T_ + t) * H_ + h]);
}

// ---------- one GRU layer stage (32 WGs) --------------------------------
// Per-step chain: poll -> 16x dwordx4 sc loads -> 48 MFMA -> LDS(parity) ->
// one __syncthreads -> gate math (regs) -> 2 dword agent stores -> vmcnt(0)
// -> per-wave flag. Gate LDS double-buffered by step parity => single barrier.
__device__ void gru_stage(
    const ushort_t* __restrict__ xin, ushort_t* __restrict__ xout,
    const ushort_t* __restrict__ Wih, const ushort_t* __restrict__ Whh,
    const float* __restrict__ bih, const float* __restrict__ bhh,
    ushort_t* __restrict__ hbuf,
    int* __restrict__ selfFl,            // [T][128] per-wave flags
    const int* __restrict__ prodFl,      // [T][prodN] (null for layer 0)
    int prodN, int wg,
    float (*Gbuf)[2][48][33])            // [parity][x/h][48][33]
{
  const int tid   = threadIdx.x;
  const int lane  = tid & 63;
  const int wave  = tid >> 6;          // 0,1 = x-GEMM; 2,3 = h-GEMM
  const int jb    = wg * CH_;
  const int m16   = lane & 15;
  const int quad  = lane >> 4;
  const int bcol  = (wave & 1) * 16 + m16;

  // Weight A-fragments resident in registers (A[m=lane&15][k=quad*8+j])
  const ushort_t* Wsel = (wave < 2) ? Wih : Whh;
  short8 afrag[3][16];
#pragma unroll
  for (int g = 0; g < 3; ++g) {
    const ushort_t* wp = Wsel + (size_t)(g * H_ + jb + m16) * H_ + quad * 8;
#pragma unroll
    for (int kk = 0; kk < 16; ++kk)
      afrag[g][kk] = *(const short8*)(wp + kk * 32);
  }

  const int b0 = tid & 31;
  const int c  = tid >> 5;
  const int c0 = 2 * c, c1 = 2 * c + 1;
  const float bxr0 = bih[0*H_ + jb + c0], bhr0 = bhh[0*H_ + jb + c0];
  const float bxz0 = bih[1*H_ + jb + c0], bhz0 = bhh[1*H_ + jb + c0];
  const float bxn0 = bih[2*H_ + jb + c0], bhn0 = bhh[2*H_ + jb + c0];
  const float bxr1 = bih[0*H_ + jb + c1], bhr1 = bhh[0*H_ + jb + c1];
  const float bxz1 = bih[1*H_ + jb + c1], bhz1 = bhh[1*H_ + jb + c1];
  const float bxn1 = bih[2*H_ + jb + c1], bhn1 = bhh[2*H_ + jb + c1];
  float hp0 = 0.f, hp1 = 0.f;          // per-thread h state in registers

  for (int s = 0; s < T_; ++s) {
    const int p = s & 1;
    f32x4 acc0 = {0.f, 0.f, 0.f, 0.f};
    f32x4 acc1 = acc0, acc2 = acc0;

    if (wave < 2) {
      const ushort_t* src = xin + ((size_t)s * B_ + bcol) * H_ + quad * 8;
      if (prodFl) {
        poll_row(prodFl + s * prodN, prodN);
        short8 bfr[16];
#pragma unroll
        for (int kk = 0; kk < 16; ++kk) cload16(bfr[kk], src + kk * 32);
        WAIT_VM0;
#pragma unroll
        for (int kk = 0; kk < 16; ++kk) {
          vfence(bfr[kk]);
          acc0 = __builtin_amdgcn_mfma_f32_16x16x32_bf16(afrag[0][kk], bfr[kk], acc0, 0, 0, 0);
          acc1 = __builtin_amdgcn_mfma_f32_16x16x32_bf16(afrag[1][kk], bfr[kk], acc1, 0, 0, 0);
          acc2 = __builtin_amdgcn_mfma_f32_16x16x32_bf16(afrag[2][kk], bfr[kk], acc2, 0, 0, 0);
        }
      } else {
        // layer 0: input from a prior dispatch -> plain cached loads
#pragma unroll
        for (int kk = 0; kk < 16; ++kk) {
          short8 bf = *(const short8*)(src + kk * 32);
          acc0 = __builtin_amdgcn_mfma_f32_16x16x32_bf16(afrag[0][kk], bf, acc0, 0, 0, 0);
          acc1 = __builtin_amdgcn_mfma_f32_16x16x32_bf16(afrag[1][kk], bf, acc1, 0, 0, 0);
          acc2 = __builtin_amdgcn_mfma_f32_16x16x32_bf16(afrag[2][kk], bf, acc2, 0, 0, 0);
        }
      }
    } else {
      if (s > 0) poll_row(selfFl + (s - 1) * 128, 128);
      const ushort_t* src = hbuf + ((size_t)p * B_ + bcol) * H_ + quad * 8;
      short8 bfr[16];
#pragma unroll
      for (int kk = 0; kk < 16; ++kk) cload16(bfr[kk], src + kk * 32);
      WAIT_VM0;
#pragma unroll
      for (int kk = 0; kk < 16; ++kk) {
        vfence(bfr[kk]);
        acc0 = __builtin_amdgcn_mfma_f32_16x16x32_bf16(afrag[0][kk], bfr[kk], acc0, 0, 0, 0);
        acc1 = __builtin_amdgcn_mfma_f32_16x16x32_bf16(afrag[1][kk], bfr[kk], acc1, 0, 0, 0);
        acc2 = __builtin_amdgcn_mfma_f32_16x16x32_bf16(afrag[2][kk], bfr[kk], acc2, 0, 0, 0);
      }
    }

    // C/D layout: col = lane&15 (batch), row = quad*4 + reg
    float (*Gd)[33] = Gbuf[p][(wave < 2) ? 0 : 1];
#pragma unroll
    for (int r = 0; r < 4; ++r) {
      Gd[ 0 + quad * 4 + r][bcol] = acc0[r];
      Gd[16 + quad * 4 + r][bcol] = acc1[r];
      Gd[32 + quad * 4 + r][bcol] = acc2[r];
    }
    __syncthreads();   // the ONLY barrier per step (parity buffers protect reuse)

    float (*Gx)[33] = Gbuf[p][0];
    float (*Gh)[33] = Gbuf[p][1];
    ushort_t* hdst = hbuf + (size_t)(p ^ 1) * B_ * H_;
    {
      float rr = fsig(Gx[c0][b0] + bxr0 + Gh[c0][b0] + bhr0);
      float zz = fsig(Gx[16 + c0][b0] + bxz0 + Gh[16 + c0][b0] + bhz0);
      float nn = ftanh(Gx[32 + c0][b0] + bxn0 + rr * (Gh[32 + c0][b0] + bhn0));
      hp0 = (1.f - zz) * nn + zz * hp0;
    }
    {
      float rr = fsig(Gx[c1][b0] + bxr1 + Gh[c1][b0] + bhr1);
      float zz = fsig(Gx[16 + c1][b0] + bxz1 + Gh[16 + c1][b0] + bhz1);
      float nn = ftanh(Gx[32 + c1][b0] + bxn1 + rr * (Gh[32 + c1][b0] + bhn1));
      hp1 = (1.f - zz) * nn + zz * hp1;
    }
    unsigned int pack = (unsigned int)f2bf(hp0) | ((unsigned int)f2bf(hp1) << 16);
    __hip_atomic_store((unsigned int*)(hdst + (size_t)b0 * H_ + jb + c0), pack,
                       __ATOMIC_RELAXED, __HIP_MEMORY_SCOPE_AGENT);
    __hip_atomic_store((unsigned int*)(xout + ((size_t)s * B_ + b0) * H_ + jb + c0), pack,
                       __ATOMIC_RELAXED, __HIP_MEMORY_SCOPE_AGENT);

    WAIT_VM0;                                   // this wave's stores now in LLC
    if (lane == 0)
      __hip_atomic_store(selfFl + s * 128 + wg * 4 + wave, 1,
                         __ATOMIC_RELAXED, __HIP_MEMORY_SCOPE_AGENT);
  }
}

// ---------- LN stage (8 WGs): mask (t>=len -> 0) + LayerNorm over H ----------
// wave v of WG w owns batch row b = w*4+v; waves fully independent (no barrier).
__device__ void ln_stage(
    const ushort_t* __restrict__ xin,
    ushort_t* __restrict__ xout_bf,       // non-null for mid-stack LN (bf16 out)
    float* __restrict__ out_f32,          // non-null for final LN (fp32 d_out)
    const float* __restrict__ gamma, const float* __restrict__ beta,
    const int* __restrict__ seq,
    int* __restrict__ selfFl,             // [T][32] per-wave(batch) flags
    const int* __restrict__ prodFl, int prodN, int wg)
{
  const int lane = threadIdx.x & 63;
  const int wv   = threadIdx.x >> 6;
  const int b    = wg * 4 + wv;
  const int len  = seq[b];
  const int h0   = lane * 8;

  float g[8], be[8];
#pragma unroll
  for (int j = 0; j < 8; ++j) { g[j] = gamma[h0 + j]; be[j] = beta[h0 + j]; }

  for (int s = 0; s < T_; ++s) {
    poll_row(prodFl + s * prodN, prodN);
    short8 raw;
    cload16(raw, xin + ((size_t)s * B_ + b) * H_ + h0);
    WAIT_VM0;
    vfence(raw);
    const bool valid = s < len;
    float v[8];
#pragma unroll
    for (int j = 0; j < 8; ++j) v[j] = valid ? bf2f((ushort_t)raw[j]) : 0.f;

    float sum = 0.f, sq = 0.f;
#pragma unroll
    for (int j = 0; j < 8; ++j) { sum += v[j]; sq += v[j] * v[j]; }
#pragma unroll
    for (int off = 32; off > 0; off >>= 1) {
      sum += __shfl_xor(sum, off);
      sq  += __shfl_xor(sq, off);
    }
    float mu   = sum * (1.f / H_);
    float var  = sq * (1.f / H_) - mu * mu;
    float rstd = rsqrtf(var + 1e-5f);

    if (xout_bf) {
      short8 o;
#pragma unroll
      for (int j = 0; j < 8; ++j)
        o[j] = (short)f2bf((v[j] - mu) * rstd * g[j] + be[j]);
      cstore16(o, xout_bf + ((size_t)s * B_ + b) * H_ + h0);
      WAIT_VM0;
      if (lane == 0)
        __hip_atomic_store(selfFl + s * 32 + b, 1,
                           __ATOMIC_RELAXED, __HIP_MEMORY_SCOPE_AGENT);
    } else {
      float* dst = out_f32 + ((size_t)b * T_ + s) * H_ + h0;
#pragma unroll
      for (int j = 0; j < 8; ++j)
        dst[j] = (v[j] - mu) * rstd * g[j] + be[j];
    }
  }
}

// ---------- fused pipelined kernel: 6 stages, grid 256, one launch ----------
// PROBE ROUND: round-0 pipeline semantics exactly (device-scope flags, same
// per-step protocol), but (1) grid 256 with bid%8 XCD-aligned role mapping
// (pure renaming of block->stage; correctness-irrelevant) and (2) a fully
// bounded co-location handshake whose result is RECORDED BUT NEVER USED.
// Every handshake spin is iteration-bounded -> cannot hang by construction.
__global__ __launch_bounds__(256, 1) void gru_mega(
    ushort_t* __restrict__ xA, ushort_t* __restrict__ xB, ushort_t* __restrict__ xC,
    const ushort_t* __restrict__ WihBf, const ushort_t* __restrict__ WhhBf,
    const float* __restrict__ bih, const float* __restrict__ bhh,
    const float* __restrict__ gamma, const float* __restrict__ beta,
    const int* __restrict__ seq,
    ushort_t* __restrict__ hbase, int* __restrict__ flbase,
    float* __restrict__ out)
{
  __shared__ float Gbuf[2][2][48][33];   // [parity][x/h]

  const int bid  = blockIdx.x;
  const int r8   = bid & 7;
  const int slot = bid >> 3;
  if (r8 >= 6) return;
  if (r8 >= 4 && slot >= 8) return;

  const int GRUF = T_ * 128;            // flag ints per GRU stage
  const int LNF  = T_ * 32;             // flag ints per LN stage
  int* fl0   = flbase;
  int* fl1   = flbase + GRUF;
  int* flln0 = flbase + 2 * GRUF;
  int* fl2   = flbase + 2 * GRUF + LNF;
  int* fl3   = flbase + 3 * GRUF + LNF;
  int* hsk   = flbase + 4 * GRUF + LNF; // tokens[4][32], votes[4][32], result[8]
  const int WM  = 3 * H_ * H_;          // elements per weight matrix
  const int HBL = 2 * B_ * H_;          // elements per h ping-pong

  // ---- inert, fully bounded co-location handshake (result unused) ----
  if (r8 < 4) {
    if (threadIdx.x < 64) {
      const int lane = threadIdx.x;
      int* t = hsk + r8 * 32;
      int* o = hsk + 128 + r8 * 32;
      int ok = 1;
      for (int round = 1; round <= 2 && ok; ++round) {
        if (lane == 0) *(volatile int*)(t + slot) = round;   // plain store
        int it = 0;
        for (;;) {
          int v;
          asm volatile("global_load_dword %0, %1, off sc0\n\ts_waitcnt vmcnt(0)"
                       : "=&v"(v) : "v"(t + (lane & 31)) : "memory");
          if (__all(v >= round && v <= 2)) break;
          if (++it > 512) { ok = 0; break; }
        }
      }
      if (lane == 0)
        __hip_atomic_store(o + slot, ok + 1,
                           __ATOMIC_RELAXED, __HIP_MEMORY_SCOPE_AGENT);
      int v2 = 0, it2 = 0;
      for (;;) {                       // bounded even though posts are guaranteed
        v2 = __hip_atomic_load(o + (lane & 31),
                               __ATOMIC_RELAXED, __HIP_MEMORY_SCOPE_AGENT);
        if (__all(v2 != 0)) break;
        if (++it2 > 100000) break;
        __builtin_amdgcn_s_sleep(1);
      }
      if (lane == 0)                   // record (never read; keeps code live)
        __hip_atomic_store(hsk + 256 + r8, __all(v2 == 2) ? 1 : 0,
                           __ATOMIC_RELAXED, __HIP_MEMORY_SCOPE_AGENT);
    }
    __syncthreads();
  }

  // ---- round-0 pipeline, re-homed onto the bid%8 mapping ----
  if (r8 == 0) {
    gru_stage(xA, xB, WihBf, WhhBf, bih, bhh,
              hbase, fl0, nullptr, 0, slot, Gbuf);
  } else if (r8 == 1) {
    gru_stage(xB, xC, WihBf + WM, WhhBf + WM, bih + 1536, bhh + 1536,
              hbase + HBL, fl1, fl0, 128, slot, Gbuf);
  } else if (r8 == 2) {
    gru_stage(xA, xC, WihBf + 2 * WM, WhhBf + 2 * WM, bih + 2 * 1536, bhh + 2 * 1536,
              hbase + 2 * HBL, fl2, flln0, 32, slot, Gbuf);
  } else if (r8 == 3) {
    gru_stage(xC, xB, WihBf + 3 * WM, WhhBf + 3 * WM, bih + 3 * 1536, bhh + 3 * 1536,
              hbase + 3 * HBL, fl3, fl2, 128, slot, Gbuf);
  } else if (r8 == 4) {
    ln_stage(xC, xA, nullptr, gamma, beta, seq, flln0, fl1, 128, slot);
  } else {
    ln_stage(xB, nullptr, out, gamma + H_, beta + H_, seq,
             nullptr, fl3, 128, slot);
  }
}

// ---------- workspace layout (bytes) ----------
#define WIH_OFF 0u
#define WHH_OFF 6291456u
#define XA_OFF  12582912u
#define XB_OFF  29360128u
#define XC_OFF  46137344u
#define HB_OFF  62914560u             // 4 * 2*32*512*2 = 262144
#define FL_OFF  63176704u             // 4*512*128*4 + 512*32*4 = 1114112 + hsk 1056
// zero region = 262144 + 1114112 + 1056 = 1377312; ws end = 64291872

extern "C" void kernel_launch(void* const* d_in, const int* in_sizes, int n_in,
                              void* d_out, int out_size, void* d_ws, size_t ws_size,
                              hipStream_t stream) {
  (void)in_sizes; (void)n_in; (void)out_size; (void)ws_size;
  const float* x     = (const float*)d_in[0];
  const float* Wih   = (const float*)d_in[1];
  const float* Whh   = (const float*)d_in[2];
  const float* bih   = (const float*)d_in[3];
  const float* bhh   = (const float*)d_in[4];
  const float* gamma = (const float*)d_in[5];
  const float* beta  = (const float*)d_in[6];
  const int*   seq   = (const int*)d_in[7];

  char* ws = (char*)d_ws;
  ushort_t* WihBf = (ushort_t*)(ws + WIH_OFF);
  ushort_t* WhhBf = (ushort_t*)(ws + WHH_OFF);
  ushort_t* xA    = (ushort_t*)(ws + XA_OFF);
  ushort_t* xB    = (ushort_t*)(ws + XB_OFF);
  ushort_t* xC    = (ushort_t*)(ws + XC_OFF);
  ushort_t* hbase = (ushort_t*)(ws + HB_OFF);
  int*      flags = (int*)(ws + FL_OFF);

  // zero h ping-pong + flags + handshake (ws is poisoned 0xAA before every call)
  hipMemsetAsync(ws + HB_OFF, 0, 1377312u, stream);

  prep_w<<<3145728 / 256, 256, 0, stream>>>(Wih, Whh, WihBf, WhhBf);
  prep_x<<<8388608 / 256, 256, 0, stream>>>(x, xA);

  gru_mega<<<256, 256, 0, stream>>>(xA, xB, xC, WihBf, WhhBf,
                                    bih, bhh, gamma, beta, seq,
                                    hbase, flags, (float*)d_out);
}